// Round 10
// baseline (301.825 us; speedup 1.0000x reference)
//
#include <hip/hip_runtime.h>

typedef __bf16 bfv8 __attribute__((ext_vector_type(8)));
typedef float f32x4 __attribute__((ext_vector_type(4)));
typedef float f32x2 __attribute__((ext_vector_type(2)));
typedef short shortv8 __attribute__((ext_vector_type(8)));
typedef unsigned short usv8 __attribute__((ext_vector_type(8)));
typedef unsigned int u32x4 __attribute__((ext_vector_type(4)));

__device__ __forceinline__ float b2f(unsigned short u) {
  unsigned int v = ((unsigned int)u) << 16;
  float f;
  __builtin_memcpy(&f, &v, 4);
  return f;
}
__device__ __forceinline__ unsigned short f2b(float f) {
  unsigned int u;
  __builtin_memcpy(&u, &f, 4);
  u += 0x7fffu + ((u >> 16) & 1u);
  return (unsigned short)(u >> 16);
}
// unpack 2 bf16 (packed in one dword, ch order lo=even, hi=odd) -> f32x2
__device__ __forceinline__ f32x2 unpack2(unsigned int u) {
  unsigned int lo = u << 16;
  unsigned int hi = u & 0xffff0000u;
  float fl, fh;
  __builtin_memcpy(&fl, &lo, 4);
  __builtin_memcpy(&fh, &hi, 4);
  f32x2 r;
  r.x = fl;
  r.y = fh;
  return r;
}

// ---------------- dtype probe (x): f32-as-bf16 shows ~48% absurd exponents ----
__global__ void probe_kernel(const unsigned short* __restrict__ x, int* __restrict__ flag) {
  int lane = threadIdx.x;  // 64 threads
  int cnt = 0;
  for (int i = lane; i < 4096; i += 64) {
    unsigned int e = (x[i] >> 7) & 0xffu;
    if (e >= 0x86u) cnt++;  // |val| >= 128
  }
#pragma unroll
  for (int off = 1; off < 64; off <<= 1) cnt += __shfl_xor(cnt, off, 64);
  if (lane == 0) *flag = (cnt > 100) ? 1 : 0;
}

// ---------------- canonicalize x to bf16 ----------------
__global__ __launch_bounds__(256) void conv_x_kernel(const void* __restrict__ x,
                                                     unsigned short* __restrict__ dst,
                                                     const int* __restrict__ flagp, int n) {
  int i = (blockIdx.x * 256 + threadIdx.x) * 4;
  if (i >= n) return;
  if (*flagp) {
    float4 f = *reinterpret_cast<const float4*>((const float*)x + i);
    ushort4 o;
    o.x = f2b(f.x); o.y = f2b(f.y); o.z = f2b(f.z); o.w = f2b(f.w);
    *reinterpret_cast<ushort4*>(dst + i) = o;
  } else {
    *reinterpret_cast<ushort4*>(dst + i) =
        *reinterpret_cast<const ushort4*>((const unsigned short*)x + i);
  }
}

// ---------------- prep params: W transposes + small vectors, converting per flag ----
// WT1[n][k] = W1[k][n] (n<512), WT2[n][k] = W2[k][n] (n<32).
// Pv (bf16): bl1@0 br1@256 att1@512 bias1@768 bl2@1024 br2@1040 att2@1056 bias2@1072
#define SM_TOT 1088
__device__ __forceinline__ unsigned short rd_param(const void* p, int e, int flag) {
  return flag ? f2b(((const float*)p)[e]) : ((const unsigned short*)p)[e];
}
__global__ __launch_bounds__(256) void prep_params_kernel(
    const void* Wl1, const void* bl1, const void* Wr1, const void* br1,
    const void* att1, const void* bias1, const void* Wl2, const void* bl2,
    const void* Wr2, const void* br2, const void* att2, const void* bias2,
    unsigned short* __restrict__ WT1, unsigned short* __restrict__ WT2,
    unsigned short* __restrict__ Pv, const int* __restrict__ flagp) {
  int idx = blockIdx.x * 256 + threadIdx.x;
  int flag = *flagp;
  if (idx < 512 * 256) {
    int n = idx >> 8, k = idx & 255;
    WT1[idx] = (n < 256) ? rd_param(Wl1, k * 256 + n, flag)
                         : rd_param(Wr1, k * 256 + (n - 256), flag);
    return;
  }
  idx -= 512 * 256;
  if (idx < 32 * 256) {
    int n = idx >> 8, k = idx & 255;
    WT2[idx] = (n < 16) ? rd_param(Wl2, k * 16 + n, flag)
                        : rd_param(Wr2, k * 16 + (n - 16), flag);
    return;
  }
  idx -= 32 * 256;
  if (idx >= SM_TOT) return;
  const void* srcs[8] = {bl1, br1, att1, bias1, bl2, br2, att2, bias2};
  const int offs[9] = {0, 256, 512, 768, 1024, 1040, 1056, 1072, SM_TOT};
  int t = 0;
  while (idx >= offs[t + 1]) t++;
  Pv[idx] = rd_param(srcs[t], idx - offs[t], flag);
}

// ---------------- GEMM1: C[M,512] = X[M,256] @ [Wl1|Wr1] + bias (bf16 out)
// m97-style: WT n-slab double-buffered in LDS (BK=64, XOR seg-swizzle); only X
// streams from HBM in the K-loop. Epilogue reuses LDS for coalesced C stores.
__global__ __launch_bounds__(256) void gemm1_kernel(
    const unsigned short* __restrict__ X,   // bf16 [M,256]
    const unsigned short* __restrict__ WT,  // bf16 [512,256]
    const unsigned short* __restrict__ bl, const unsigned short* __restrict__ br,
    unsigned short* __restrict__ C, int M) {
  __shared__ unsigned short smem[18432];  // 36864B: K-loop 2x8192, epilogue 4x4608
  const int t = threadIdx.x;
  const int lane = t & 63;
  const int w = t >> 6;
  const int quad = lane >> 4;
  const int l16 = lane & 15;
  const int n_blk = blockIdx.x;  // 0..3 fastest -> 4 siblings share the X slab in L2
  const int m_base = blockIdx.y * 128 + (w >> 1) * 64;
  const int n_base = n_blk * 128 + (w & 1) * 64;

  const int st_row = t >> 3;
  const int st_seg = t & 7;
  const unsigned short* wt_base =
      WT + ((size_t)(n_blk * 128 + st_row)) * 256 + st_seg * 8;

  f32x4 acc[4][4];
#pragma unroll
  for (int i = 0; i < 4; i++)
#pragma unroll
    for (int j = 0; j < 4; j++) acc[i][j] = (f32x4){0.f, 0.f, 0.f, 0.f};

  shortv8 st[4];
#pragma unroll
  for (int i = 0; i < 4; i++)
    st[i] = *reinterpret_cast<const shortv8*>(wt_base + (size_t)(32 * i) * 256);
#pragma unroll
  for (int i = 0; i < 4; i++) {
    int row = st_row + 32 * i;
    *reinterpret_cast<shortv8*>(smem + row * 64 + ((st_seg ^ (row & 7)) * 8)) = st[i];
  }
  __syncthreads();

#pragma unroll
  for (int c = 0; c < 4; c++) {
    if (c < 3) {
#pragma unroll
      for (int i = 0; i < 4; i++)
        st[i] = *reinterpret_cast<const shortv8*>(wt_base + (size_t)(32 * i) * 256 +
                                                  (c + 1) * 64);
    }
    const unsigned short* bb = smem + (c & 1) * 8192;
#pragma unroll
    for (int sub = 0; sub < 2; sub++) {
      bfv8 a[4], b[4];
      int seg_r = sub * 4 + quad;  // 0..7
#pragma unroll
      for (int i = 0; i < 4; i++) {
        int row = m_base + 16 * i + l16;
        if (row >= M) row = M - 1;
        a[i] = *reinterpret_cast<const bfv8*>(X + (size_t)row * 256 + c * 64 + sub * 32 +
                                              quad * 8);
      }
#pragma unroll
      for (int j = 0; j < 4; j++) {
        int col = (w & 1) * 64 + 16 * j + l16;  // n within the 128-slab
        b[j] = *reinterpret_cast<const bfv8*>(bb + col * 64 + ((seg_r ^ (col & 7)) * 8));
      }
#pragma unroll
      for (int i = 0; i < 4; i++)
#pragma unroll
        for (int j = 0; j < 4; j++)
          acc[i][j] = __builtin_amdgcn_mfma_f32_16x16x32_bf16(a[i], b[j], acc[i][j], 0, 0, 0);
    }
    if (c < 3) {
      int buf = (c + 1) & 1;
#pragma unroll
      for (int i = 0; i < 4; i++) {
        int row = st_row + 32 * i;
        *reinterpret_cast<shortv8*>(smem + buf * 8192 + row * 64 +
                                    ((st_seg ^ (row & 7)) * 8)) = st[i];
      }
      __syncthreads();
    }
  }

  __syncthreads();
  unsigned short* lt = smem + w * 4608;
#pragma unroll
  for (int j = 0; j < 4; j++) {
    int col = n_base + 16 * j + l16;
    float bias = (col < 256) ? b2f(bl[col]) : b2f(br[col - 256]);
#pragma unroll
    for (int i = 0; i < 4; i++)
#pragma unroll
      for (int r = 0; r < 4; r++)
        lt[(16 * i + quad * 4 + r) * 72 + 16 * j + l16] = f2b(acc[i][j][r] + bias);
  }
#pragma unroll
  for (int pass = 0; pass < 8; pass++) {
    int row = pass * 8 + (lane >> 3);
    int colg = (lane & 7) * 8;
    shortv8 v = *reinterpret_cast<const shortv8*>(lt + row * 72 + colg);
    int grow = m_base + row;
    if (grow < M)
      *reinterpret_cast<shortv8*>(C + (size_t)grow * 512 + n_base + colg) = v;
  }
}

// ---------------- GEMM2: C2[M,32] = H[M,256] @ [Wl2|Wr2] + bias (f32 out)
__global__ __launch_bounds__(256) void gemm2_kernel(
    const unsigned short* __restrict__ H, const unsigned short* __restrict__ WT,
    const unsigned short* __restrict__ bl, const unsigned short* __restrict__ br,
    float* __restrict__ C, int M) {
  const int lane = threadIdx.x & 63;
  const int w = threadIdx.x >> 6;
  const int quad = lane >> 4;
  const int l16 = lane & 15;
  const int m_base = blockIdx.x * 256 + w * 64;

  f32x4 acc[4][2];
#pragma unroll
  for (int i = 0; i < 4; i++)
#pragma unroll
    for (int j = 0; j < 2; j++) acc[i][j] = (f32x4){0.f, 0.f, 0.f, 0.f};

#pragma unroll
  for (int k0 = 0; k0 < 256; k0 += 32) {
    bfv8 a[4], b[2];
#pragma unroll
    for (int i = 0; i < 4; i++) {
      int row = m_base + 16 * i + l16;
      if (row >= M) row = M - 1;
      a[i] = *reinterpret_cast<const bfv8*>(H + (size_t)row * 256 + k0 + quad * 8);
    }
#pragma unroll
    for (int j = 0; j < 2; j++) {
      int col = 16 * j + l16;
      b[j] = *reinterpret_cast<const bfv8*>(WT + (size_t)col * 256 + k0 + quad * 8);
    }
#pragma unroll
    for (int i = 0; i < 4; i++)
#pragma unroll
      for (int j = 0; j < 2; j++)
        acc[i][j] = __builtin_amdgcn_mfma_f32_16x16x32_bf16(a[i], b[j], acc[i][j], 0, 0, 0);
  }

#pragma unroll
  for (int j = 0; j < 2; j++) {
    int col = 16 * j + l16;
    float bias = (j == 0) ? b2f(bl[l16]) : b2f(br[l16]);
#pragma unroll
    for (int i = 0; i < 4; i++) {
#pragma unroll
      for (int r = 0; r < 4; r++) {
        int row = m_base + 16 * i + quad * 4 + r;
        if (row < M) C[(size_t)row * 32 + col] = acc[i][j][r] + bias;
      }
    }
  }
}

// ---------------- CSR build: count + 3-kernel multi-block scan + fill ----------------
__global__ __launch_bounds__(256) void count_kernel(const int* __restrict__ ei, int E, int Nn,
                                                    int* __restrict__ cnt) {
  int i = blockIdx.x * 256 + threadIdx.x;
  int total = E + Nn;
  if (i >= total) return;
  int d = (i < E) ? ei[E + i] : (i - E);
  if ((unsigned)d >= (unsigned)Nn) d = 0;
  atomicAdd(&cnt[d], 1);
}

__global__ __launch_bounds__(1024) void scan1_kernel(const int* __restrict__ cnt,
                                                     int* __restrict__ row_start,
                                                     int* __restrict__ blkTot, int Nn) {
  __shared__ int buf[1024];
  int t = threadIdx.x;
  int i = blockIdx.x * 1024 + t;
  int v = (i < Nn) ? cnt[i] : 0;
  buf[t] = v;
  __syncthreads();
  for (int off = 1; off < 1024; off <<= 1) {
    int x = (t >= off) ? buf[t - off] : 0;
    __syncthreads();
    buf[t] += x;
    __syncthreads();
  }
  if (i < Nn) row_start[i] = buf[t] - v;  // block-local exclusive
  if (t == 1023) blkTot[blockIdx.x] = buf[1023];
}

__global__ __launch_bounds__(64) void scan2_kernel(const int* __restrict__ blkTot,
                                                   int* __restrict__ blkOff, int nb,
                                                   int* __restrict__ row_start, int Nn,
                                                   int total) {
  int lane = threadIdx.x;  // nb <= 64
  int v = (lane < nb) ? blkTot[lane] : 0;
  int s = v;
#pragma unroll
  for (int off = 1; off < 64; off <<= 1) {
    int u = __shfl_up(s, off, 64);
    if (lane >= off) s += u;
  }
  if (lane < nb) blkOff[lane] = s - v;
  if (lane == 0) row_start[Nn] = total;
}

__global__ __launch_bounds__(1024) void scan3_kernel(int* __restrict__ row_start,
                                                     int* __restrict__ cursor,
                                                     const int* __restrict__ blkOff, int Nn) {
  int i = blockIdx.x * 1024 + threadIdx.x;
  if (i < Nn) {
    int val = row_start[i] + blkOff[blockIdx.x];
    row_start[i] = val;
    cursor[i] = val;
  }
}

__global__ __launch_bounds__(256) void fill_kernel(const int* __restrict__ ei, int E, int Nn,
                                                   int* __restrict__ cursor,
                                                   int* __restrict__ csr_src) {
  int i = blockIdx.x * 256 + threadIdx.x;
  int total = E + Nn;
  if (i >= total) return;
  int s, d;
  if (i < E) { s = ei[i]; d = ei[E + i]; } else { s = i - E; d = i - E; }
  if ((unsigned)d >= (unsigned)Nn) d = 0;
  if ((unsigned)s >= (unsigned)Nn) s = 0;
  int pos = atomicAdd(&cursor[d], 1);
  if ((unsigned)pos < (unsigned)total) csr_src[pos] = s;
}

// ---------------- layer-1 aggregation: 2 edges/iter, packed-f32x2 math + tanh ----
// lanes 0-31 = edge A, 32-63 = edge B; lane owns 8 ch (4 f32x2). Head = 8-lane
// group; score reduce = xor {1,2,4}. Channel math uses v_pk_* packed fp32.
__global__ __launch_bounds__(256) void agg1_kernel(
    const unsigned short* __restrict__ C1,    // [N,512]: 0-255 xl, 256-511 xr
    const unsigned short* __restrict__ att1,  // [256]
    const unsigned short* __restrict__ bias1, // [256]
    const int* __restrict__ row_start, const int* __restrict__ csr_src,
    unsigned short* __restrict__ H1,          // [N,256] bf16
    int Nn, int Etot) {
  int wid = blockIdx.x * 4 + (threadIdx.x >> 6);
  if (wid >= Nn) return;
  int lane = threadIdx.x & 63;
  int half = lane >> 5;
  int c0 = (lane & 31) * 8;

  f32x2 at2[4], xr2[4];
  {
    u32x4 a4 = *reinterpret_cast<const u32x4*>(att1 + c0);
    u32x4 r4 = *reinterpret_cast<const u32x4*>(C1 + (size_t)wid * 512 + 256 + c0);
#pragma unroll
    for (int k = 0; k < 4; k++) { at2[k] = unpack2(a4[k]); xr2[k] = unpack2(r4[k]); }
  }

  float denom = 0.f;
  f32x2 acc2[4] = {{0.f, 0.f}, {0.f, 0.f}, {0.f, 0.f}, {0.f, 0.f}};
  int beg = row_start[wid], end = row_start[wid + 1];
  if (beg < 0) beg = 0;
  if (end < beg || end - beg > Etot) end = beg;

#pragma unroll 2
  for (int i = beg; i < end; i += 2) {
    int p = i + half;
    bool valid = p < end;
    int pc = valid ? p : i;
    int s = csr_src[pc];
    if ((unsigned)s >= (unsigned)Nn) s = 0;
    u32x4 row = *reinterpret_cast<const u32x4*>(C1 + (size_t)s * 512 + c0);
    f32x2 xl2[4];
    f32x2 dot2 = {0.f, 0.f};
#pragma unroll
    for (int k = 0; k < 4; k++) {
      xl2[k] = unpack2(row[k]);
      f32x2 m2 = xl2[k] + xr2[k];
      f32x2 l2 = __builtin_elementwise_max(m2, 0.2f * m2);  // leaky (pk_mul+pk_max)
      dot2 = l2 * at2[k] + dot2;                            // pk_fma
    }
    float dot = dot2.x + dot2.y;
    dot += __shfl_xor(dot, 1, 64);
    dot += __shfl_xor(dot, 2, 64);
    dot += __shfl_xor(dot, 4, 64);  // head score in all 8 lanes of the group
    dot = fminf(fmaxf(dot, -60.f), 60.f);
    float wgt = valid ? __expf(dot) : 0.f;
    denom += wgt;
    f32x2 w2 = {wgt, wgt};
#pragma unroll
    for (int k = 0; k < 4; k++) acc2[k] = xl2[k] * w2 + acc2[k];  // pk_fma
  }
  // merge halves
  denom += __shfl_xor(denom, 32, 64);
#pragma unroll
  for (int k = 0; k < 4; k++) {
    acc2[k].x += __shfl_xor(acc2[k].x, 32, 64);
    acc2[k].y += __shfl_xor(acc2[k].y, 32, 64);
  }

  if (half == 0) {
    float inv = 1.f / (denom + 1e-16f);
    usv8 b8 = *reinterpret_cast<const usv8*>(bias1 + c0);
    usv8 o8;
#pragma unroll
    for (int k = 0; k < 4; k++) {
#pragma unroll
      for (int j = 0; j < 2; j++) {
        float x = (j ? acc2[k].y : acc2[k].x) * inv + b2f(b8[2 * k + j]);
        float e2 = __expf(2.f * x);
        float th = (e2 - 1.f) / (e2 + 1.f);
        if (!(th == th)) th = 0.f;
        o8[2 * k + j] = f2b(th);
      }
    }
    *reinterpret_cast<usv8*>(H1 + (size_t)wid * 256 + c0) = o8;
  }
}

// ---------------- layer-2 aggregation: 16 edges/iter, packed math + log_softmax ----
__global__ __launch_bounds__(256) void agg2_kernel(
    const float* __restrict__ C2,             // [N,32]: 0-15 xl2, 16-31 xr2
    const unsigned short* __restrict__ att2,  // [16]
    const unsigned short* __restrict__ bias2, // [16]
    const int* __restrict__ row_start, const int* __restrict__ csr_src,
    float* __restrict__ out,                  // [2*N*16] f32 (o, log_softmax)
    int Nn, int Etot) {
  int wid = blockIdx.x * 4 + (threadIdx.x >> 6);
  if (wid >= Nn) return;
  int lane = threadIdx.x & 63;
  int eslot = lane >> 2;
  int cg = (lane & 3) * 4;

  f32x2 at2[2], xr2[2];
  {
    ushort4 a4 = *reinterpret_cast<const ushort4*>(att2 + cg);
    at2[0].x = b2f(a4.x); at2[0].y = b2f(a4.y);
    at2[1].x = b2f(a4.z); at2[1].y = b2f(a4.w);
    float4 r4 = *reinterpret_cast<const float4*>(C2 + (size_t)wid * 32 + 16 + cg);
    xr2[0].x = r4.x; xr2[0].y = r4.y; xr2[1].x = r4.z; xr2[1].y = r4.w;
  }

  float denom = 0.f;
  f32x2 acc2[2] = {{0.f, 0.f}, {0.f, 0.f}};
  int beg = row_start[wid], end = row_start[wid + 1];
  if (beg < 0) beg = 0;
  if (end < beg || end - beg > Etot) end = beg;

  for (int i = beg; i < end; i += 16) {
    int p = i + eslot;
    bool valid = p < end;
    int pc = valid ? p : i;
    int s = csr_src[pc];
    if ((unsigned)s >= (unsigned)Nn) s = 0;
    float4 x4 = *reinterpret_cast<const float4*>(C2 + (size_t)s * 32 + cg);
    f32x2 xl2[2];
    xl2[0].x = x4.x; xl2[0].y = x4.y; xl2[1].x = x4.z; xl2[1].y = x4.w;
    f32x2 dot2 = {0.f, 0.f};
#pragma unroll
    for (int k = 0; k < 2; k++) {
      f32x2 m2 = xl2[k] + xr2[k];
      f32x2 l2 = __builtin_elementwise_max(m2, 0.2f * m2);
      dot2 = l2 * at2[k] + dot2;
    }
    float dot = dot2.x + dot2.y;
    dot += __shfl_xor(dot, 1, 64);
    dot += __shfl_xor(dot, 2, 64);  // edge score in all 4 lanes of the slot
    dot = fminf(fmaxf(dot, -60.f), 60.f);
    float wgt = valid ? __expf(dot) : 0.f;
    denom += wgt;
    f32x2 w2 = {wgt, wgt};
#pragma unroll
    for (int k = 0; k < 2; k++) acc2[k] = xl2[k] * w2 + acc2[k];
  }
#pragma unroll
  for (int off = 4; off <= 32; off <<= 1) {
    denom += __shfl_xor(denom, off, 64);
#pragma unroll
    for (int k = 0; k < 2; k++) {
      acc2[k].x += __shfl_xor(acc2[k].x, off, 64);
      acc2[k].y += __shfl_xor(acc2[k].y, off, 64);
    }
  }

  float inv = 1.f / (denom + 1e-16f);
  ushort4 b4 = *reinterpret_cast<const ushort4*>(bias2 + cg);
  float bb[4] = {b2f(b4.x), b2f(b4.y), b2f(b4.z), b2f(b4.w)};
  float o[4] = {acc2[0].x * inv + bb[0], acc2[0].y * inv + bb[1],
                acc2[1].x * inv + bb[2], acc2[1].y * inv + bb[3]};
#pragma unroll
  for (int k = 0; k < 4; k++)
    if (!(o[k] == o[k])) o[k] = 0.f;
  float mx = fmaxf(fmaxf(o[0], o[1]), fmaxf(o[2], o[3]));
  mx = fmaxf(mx, __shfl_xor(mx, 1, 64));
  mx = fmaxf(mx, __shfl_xor(mx, 2, 64));
  float se = 0.f;
#pragma unroll
  for (int k = 0; k < 4; k++) se += __expf(o[k] - mx);
  se += __shfl_xor(se, 1, 64);
  se += __shfl_xor(se, 2, 64);
  float ls = logf(se);
  if (lane < 4) {
    float4 vo = {o[0], o[1], o[2], o[3]};
    float4 vl = {o[0] - mx - ls, o[1] - mx - ls, o[2] - mx - ls, o[3] - mx - ls};
    *reinterpret_cast<float4*>(out + (size_t)wid * 16 + cg) = vo;
    *reinterpret_cast<float4*>(out + (size_t)Nn * 16 + (size_t)wid * 16 + cg) = vl;
  }
}

extern "C" void kernel_launch(void* const* d_in, const int* in_sizes, int n_in,
                              void* d_out, int out_size, void* d_ws, size_t ws_size,
                              hipStream_t stream) {
  const void* x_raw = d_in[0];
  const int* ei     = (const int*)d_in[1];

  const int M = in_sizes[0] / 256;  // nodes (50000)
  const int E = in_sizes[1] / 2;    // raw edges (400000)
  const int TOT = E + M;            // edges incl. self-loops
  const int NX = M * 256;

  char* ws = (char*)d_ws;
  size_t off = 0;
  auto alloc = [&](size_t bytes) -> void* {
    void* p = ws + off;
    off = (off + bytes + 255) & ~(size_t)255;
    return p;
  };
  int*            flag   = (int*)alloc(4);
  unsigned short* Pv     = (unsigned short*)alloc((size_t)SM_TOT * 2);
  unsigned short* Xc     = (unsigned short*)alloc((size_t)NX * 2);
  unsigned short* WT1    = (unsigned short*)alloc((size_t)512 * 256 * 2);
  unsigned short* WT2    = (unsigned short*)alloc((size_t)32 * 256 * 2);
  int*            cnt    = (int*)alloc((size_t)M * 4);
  int*            cursor = (int*)alloc((size_t)M * 4);
  int*            row_start = (int*)alloc((size_t)(M + 1) * 4);
  int*            csr_src   = (int*)alloc((size_t)TOT * 4);
  int*            blkTot = (int*)alloc(64 * 4);
  int*            blkOff = (int*)alloc(64 * 4);
  float*          C2     = (float*)alloc((size_t)M * 32 * 4);
  unsigned short* C1     = (unsigned short*)alloc((size_t)M * 512 * 2);
  const size_t need = off;
  (void)n_in;
  // H1 aliases Xc: gemm1 is the last reader of Xc; agg1 writes H1 later.
  unsigned short* H1 = Xc;

  if (ws_size < need) {
    hipMemsetAsync(d_out, 0, (size_t)out_size * 4, stream);
    return;
  }

  unsigned short* bl1c   = Pv + 0;
  unsigned short* br1c   = Pv + 256;
  unsigned short* att1c  = Pv + 512;
  unsigned short* bias1c = Pv + 768;
  unsigned short* bl2c   = Pv + 1024;
  unsigned short* br2c   = Pv + 1040;
  unsigned short* att2c  = Pv + 1056;
  unsigned short* bias2c = Pv + 1072;

  hipMemsetAsync(cnt, 0, (size_t)M * 4, stream);

  probe_kernel<<<1, 64, 0, stream>>>((const unsigned short*)x_raw, flag);
  conv_x_kernel<<<(NX / 4 + 255) / 256, 256, 0, stream>>>(x_raw, Xc, flag, NX);
  prep_params_kernel<<<(512 * 256 + 32 * 256 + SM_TOT + 255) / 256, 256, 0, stream>>>(
      d_in[2], d_in[3], d_in[4], d_in[5], d_in[6], d_in[7], d_in[8], d_in[9],
      d_in[10], d_in[11], d_in[12], d_in[13], WT1, WT2, Pv, flag);

  dim3 g1(4, (M + 127) / 128);  // n-blocks fastest: 4 siblings share X slab in L2
  gemm1_kernel<<<g1, 256, 0, stream>>>(Xc, WT1, bl1c, br1c, C1, M);

  count_kernel<<<(TOT + 255) / 256, 256, 0, stream>>>(ei, E, M, cnt);
  int nb = (M + 1023) / 1024;
  scan1_kernel<<<nb, 1024, 0, stream>>>(cnt, row_start, blkTot, M);
  scan2_kernel<<<1, 64, 0, stream>>>(blkTot, blkOff, nb, row_start, M, TOT);
  scan3_kernel<<<nb, 1024, 0, stream>>>(row_start, cursor, blkOff, M);
  fill_kernel<<<(TOT + 255) / 256, 256, 0, stream>>>(ei, E, M, cursor, csr_src);

  agg1_kernel<<<(M + 3) / 4, 256, 0, stream>>>(C1, att1c, bias1c, row_start, csr_src,
                                               H1, M, TOT);

  gemm2_kernel<<<(M + 255) / 256, 256, 0, stream>>>(H1, WT2, bl2c, br2c, C2, M);

  agg2_kernel<<<(M + 3) / 4, 256, 0, stream>>>(C2, att2c, bias2c, row_start, csr_src,
                                               (float*)d_out, M, TOT);
}